// Round 4
// baseline (3363.894 us; speedup 1.0000x reference)
//
#include <hip/hip_runtime.h>
#include <math.h>

#define NN 2048
#define CXX 768
#define CSS 384
#define HH 16
#define DHH 48
#define KSPLIT 4

typedef short bf16x8 __attribute__((ext_vector_type(8)));
typedef float f32x4 __attribute__((ext_vector_type(4)));

#define MFMA16(a,b,c) __builtin_amdgcn_mfma_f32_16x16x32_bf16(a,b,c,0,0,0)

__device__ __forceinline__ unsigned short f2bf(float f){
  unsigned u = __float_as_uint(f);
  u += 0x7FFFu + ((u >> 16) & 1u);
  return (unsigned short)(u >> 16);
}
__device__ __forceinline__ float bf2f(unsigned short u){
  return __uint_as_float(((unsigned)u) << 16);
}
__device__ __forceinline__ void async_copy16(const void* g, void* l){
  __builtin_amdgcn_global_load_lds((const __attribute__((address_space(1))) void*)g,
                                   (__attribute__((address_space(3))) void*)l, 16, 0, 0);
}

__device__ inline float waveReduceSum(float v){
  #pragma unroll
  for(int o=32;o>0;o>>=1) v += __shfl_xor(v,o);
  return v;
}

// ---------------- batched weight fp32 -> bf16 transpose (all 8 matrices) ----------
__global__ __launch_bounds__(256) void transpose_all(
    const float* __restrict__ s0, const float* __restrict__ s1, const float* __restrict__ s2,
    const float* __restrict__ s3, const float* __restrict__ s4, const float* __restrict__ s5,
    const float* __restrict__ s6, const float* __restrict__ s7,
    unsigned short* __restrict__ d_scale, unsigned short* __restrict__ d_bias,
    unsigned short* __restrict__ d_azc, unsigned short* __restrict__ d_qkvg,
    unsigned short* __restrict__ d_out){
  int z = blockIdx.z;
  const float* W; unsigned short* Wt; int K;
  switch(z){
    case 0: W=s0; Wt=d_scale; K=384; break;
    case 1: W=s1; Wt=d_bias;  K=384; break;
    case 2: W=s2; Wt=d_azc;   K=384; break;
    case 3: W=s3; Wt=d_qkvg + 0*589824; K=768; break;
    case 4: W=s4; Wt=d_qkvg + 1*589824; K=768; break;
    case 5: W=s5; Wt=d_qkvg + 2*589824; K=768; break;
    case 6: W=s6; Wt=d_qkvg + 3*589824; K=768; break;
    default: W=s7; Wt=d_out; K=768; break;
  }
  int n0 = blockIdx.x*32, k0 = blockIdx.y*32;
  if(k0 >= K) return;
  __shared__ unsigned short t[32][33];
  int c = threadIdx.x & 31, r = threadIdx.x >> 5;
  #pragma unroll
  for(int i=0;i<32;i+=8){
    float v = W[(size_t)(k0 + r + i)*CXX + n0 + c];
    t[c][r+i] = f2bf(v);
  }
  __syncthreads();
  #pragma unroll
  for(int i=0;i<32;i+=8){
    Wt[(size_t)(n0 + r + i)*K + k0 + c] = t[r+i][c];
  }
}

// ---------------- fused LayerNorms: x (fp32 out) + single_cond (bf16 out) ----------
__global__ __launch_bounds__(384) void ln_fused(const float* __restrict__ x,
    const float* __restrict__ scin, const float* __restrict__ w,
    float* __restrict__ xn, unsigned short* __restrict__ scb){
  int row = blockIdx.x;
  int t = threadIdx.x;
  int wid = t>>6, lane = t&63;
  __shared__ float red[6];
  float a0 = x[(size_t)row*CXX + t];
  float a1 = x[(size_t)row*CXX + 384 + t];
  float s = waveReduceSum(a0+a1);
  if(lane==0) red[wid]=s;
  __syncthreads();
  float mu = (red[0]+red[1]+red[2]+red[3]+red[4]+red[5]) * (1.0f/CXX);
  float d0=a0-mu, d1=a1-mu;
  float q = waveReduceSum(d0*d0+d1*d1);
  __syncthreads();
  if(lane==0) red[wid]=q;
  __syncthreads();
  float var = (red[0]+red[1]+red[2]+red[3]+red[4]+red[5]) * (1.0f/CXX);
  float r = rsqrtf(var + 1e-5f);
  xn[(size_t)row*CXX + t] = d0*r;
  xn[(size_t)row*CXX + 384 + t] = d1*r;
  float b = scin[(size_t)row*CSS + t];
  float s2 = waveReduceSum(b);
  __syncthreads();
  if(lane==0) red[wid]=s2;
  __syncthreads();
  float mu2 = (red[0]+red[1]+red[2]+red[3]+red[4]+red[5]) * (1.0f/CSS);
  float d2 = b - mu2;
  float q2 = waveReduceSum(d2*d2);
  __syncthreads();
  if(lane==0) red[wid]=q2;
  __syncthreads();
  float var2 = (red[0]+red[1]+red[2]+red[3]+red[4]+red[5]) * (1.0f/CSS);
  float r2 = rsqrtf(var2 + 1e-5f);
  scb[(size_t)row*CSS + t] = f2bf(d2*r2*w[t]);
}

// ---------------- qkvg GEMM (128x128 tile, BK=32): q/k/gate -> qkvg, v -> vt^T ------
__global__ __launch_bounds__(256) void gemm_qkvg(const unsigned short* __restrict__ A,
    const unsigned short* __restrict__ Bt, const float* __restrict__ bias,
    unsigned short* __restrict__ C, unsigned short* __restrict__ vt){
  __shared__ unsigned short As[128*32];
  __shared__ unsigned short Bs[128*32];
  const int tid = threadIdx.x;
  const int w = tid>>6, lane = tid&63;
  const int ln15 = lane&15, hi = lane>>4;
  const int wm = w&1, wn = w>>1;
  const int m0 = blockIdx.y*128, n0 = blockIdx.x*128;
  const int lrow = lane>>2, lk = (lane&3)*8;
  const int K = 768, NC = 3072;

  f32x4 z = {0.f,0.f,0.f,0.f};
  f32x4 acc[4][4];
  #pragma unroll
  for(int i=0;i<4;i++)
    #pragma unroll
    for(int j=0;j<4;j++) acc[i][j] = z;

  for(int k0=0;k0<K;k0+=32){
    const unsigned short* ga = A + (size_t)(m0 + w*32 + lrow)*K + k0 + lk;
    const unsigned short* gb = Bt + (size_t)(n0 + w*32 + lrow)*K + k0 + lk;
    async_copy16(ga,          &As[w*1024]);
    async_copy16(ga + 16*K,   &As[w*1024 + 512]);
    async_copy16(gb,          &Bs[w*1024]);
    async_copy16(gb + 16*K,   &Bs[w*1024 + 512]);
    __syncthreads();
    bf16x8 af[4], bfr[4];
    #pragma unroll
    for(int i=0;i<4;i++) af[i]  = *(const bf16x8*)&As[(wm*64 + i*16 + ln15)*32 + hi*8];
    #pragma unroll
    for(int j=0;j<4;j++) bfr[j] = *(const bf16x8*)&Bs[(wn*64 + j*16 + ln15)*32 + hi*8];
    #pragma unroll
    for(int i=0;i<4;i++)
      #pragma unroll
      for(int j=0;j<4;j++)
        acc[i][j] = MFMA16(af[i], bfr[j], acc[i][j]);
    __syncthreads();
  }

  #pragma unroll
  for(int i=0;i<4;i++)
    #pragma unroll
    for(int j=0;j<4;j++){
      int gm0 = m0 + wm*64 + i*16 + hi*4;
      int gn  = n0 + wn*64 + j*16 + ln15;
      if(gn >= 1536 && gn < 2304){
        // V projection: store transposed vt[d_global][key], keys contiguous
        ushort4 v4;
        v4.x = f2bf(acc[i][j][0]);
        v4.y = f2bf(acc[i][j][1]);
        v4.z = f2bf(acc[i][j][2]);
        v4.w = f2bf(acc[i][j][3]);
        *(ushort4*)&vt[(size_t)(gn - 1536)*NN + gm0] = v4;
      } else {
        #pragma unroll
        for(int r=0;r<4;r++){
          float v = acc[i][j][r];
          if(gn < 768) v += bias[gn];
          if(gn >= 2304) v = 1.0f/(1.0f + __expf(-v));
          C[(size_t)(gm0+r)*NC + gn] = f2bf(v);
        }
      }
    }
}

// ---------------- AdaLN triple-GEMM (64x64 tile, BK=32, 384 blocks) ----------------
__global__ __launch_bounds__(256) void adaln3(const unsigned short* __restrict__ A,
    const unsigned short* __restrict__ B1, const unsigned short* __restrict__ B2,
    const unsigned short* __restrict__ B3, const float* __restrict__ bs,
    const float* __restrict__ zb, const float* __restrict__ xn,
    unsigned short* __restrict__ xa, float* __restrict__ azc){
  __shared__ unsigned short As[64*32];
  __shared__ unsigned short Bs1[64*32];
  __shared__ unsigned short Bs2[64*32];
  __shared__ unsigned short Bs3[64*32];
  const int tid = threadIdx.x;
  const int w = tid>>6, lane = tid&63;
  const int ln15 = lane&15, hi = lane>>4;
  const int wm = w&1, wn = w>>1;
  const int m0 = blockIdx.y*64, n0 = blockIdx.x*64;
  const int lrow = tid>>2, lk = (tid&3)*8;
  const int K = CSS;

  f32x4 z = {0.f,0.f,0.f,0.f};
  f32x4 acc1[2][2], acc2[2][2], acc3[2][2];
  #pragma unroll
  for(int i=0;i<2;i++)
    #pragma unroll
    for(int j=0;j<2;j++){ acc1[i][j]=z; acc2[i][j]=z; acc3[i][j]=z; }

  for(int k0=0;k0<K;k0+=32){
    async_copy16(A  + (size_t)(m0+lrow)*K + k0 + lk, &As [w*512]);
    async_copy16(B1 + (size_t)(n0+lrow)*K + k0 + lk, &Bs1[w*512]);
    async_copy16(B2 + (size_t)(n0+lrow)*K + k0 + lk, &Bs2[w*512]);
    async_copy16(B3 + (size_t)(n0+lrow)*K + k0 + lk, &Bs3[w*512]);
    __syncthreads();
    bf16x8 af[2], b1f[2], b2f[2], b3f[2];
    #pragma unroll
    for(int i=0;i<2;i++) af[i]  = *(const bf16x8*)&As[(wm*32 + i*16 + ln15)*32 + hi*8];
    #pragma unroll
    for(int j=0;j<2;j++){
      b1f[j] = *(const bf16x8*)&Bs1[(wn*32 + j*16 + ln15)*32 + hi*8];
      b2f[j] = *(const bf16x8*)&Bs2[(wn*32 + j*16 + ln15)*32 + hi*8];
      b3f[j] = *(const bf16x8*)&Bs3[(wn*32 + j*16 + ln15)*32 + hi*8];
    }
    #pragma unroll
    for(int i=0;i<2;i++)
      #pragma unroll
      for(int j=0;j<2;j++){
        acc1[i][j] = MFMA16(af[i], b1f[j], acc1[i][j]);
        acc2[i][j] = MFMA16(af[i], b2f[j], acc2[i][j]);
        acc3[i][j] = MFMA16(af[i], b3f[j], acc3[i][j]);
      }
    __syncthreads();
  }

  #pragma unroll
  for(int i=0;i<2;i++)
    #pragma unroll
    for(int j=0;j<2;j++)
      #pragma unroll
      for(int r=0;r<4;r++){
        int gm = m0 + wm*32 + i*16 + hi*4 + r;
        int gn = n0 + wn*32 + j*16 + ln15;
        float g = 1.0f/(1.0f + __expf(-(acc1[i][j][r] + bs[gn])));
        float v = g * xn[(size_t)gm*CXX + gn] + acc2[i][j][r];
        xa[(size_t)gm*CXX + gn] = f2bf(v);
        azc[(size_t)gm*CXX + gn] = 1.0f/(1.0f + __expf(-(acc3[i][j][r] + zb[gn])));
      }
}

// ---------------- out GEMM (64x64 tile, BK=32): out = (wag @ out_w) * azc, fp32 ----------
__global__ __launch_bounds__(256) void gemm_out(const unsigned short* __restrict__ A,
    const unsigned short* __restrict__ Bt, const float* __restrict__ mul,
    float* __restrict__ C){
  __shared__ unsigned short As[64*32];
  __shared__ unsigned short Bs[64*32];
  const int tid = threadIdx.x;
  const int w = tid>>6, lane = tid&63;
  const int ln15 = lane&15, hi = lane>>4;
  const int wm = w&1, wn = w>>1;
  const int m0 = blockIdx.y*64, n0 = blockIdx.x*64;
  const int lrow = tid>>2, lk = (tid&3)*8;
  const int K = 768;

  f32x4 z = {0.f,0.f,0.f,0.f};
  f32x4 acc[2][2];
  #pragma unroll
  for(int i=0;i<2;i++)
    #pragma unroll
    for(int j=0;j<2;j++) acc[i][j]=z;

  for(int k0=0;k0<K;k0+=32){
    async_copy16(A  + (size_t)(m0+lrow)*K + k0 + lk, &As[w*512]);
    async_copy16(Bt + (size_t)(n0+lrow)*K + k0 + lk, &Bs[w*512]);
    __syncthreads();
    bf16x8 af[2], bfr[2];
    #pragma unroll
    for(int i=0;i<2;i++) af[i]  = *(const bf16x8*)&As[(wm*32 + i*16 + ln15)*32 + hi*8];
    #pragma unroll
    for(int j=0;j<2;j++) bfr[j] = *(const bf16x8*)&Bs[(wn*32 + j*16 + ln15)*32 + hi*8];
    #pragma unroll
    for(int i=0;i<2;i++)
      #pragma unroll
      for(int j=0;j<2;j++)
        acc[i][j] = MFMA16(af[i], bfr[j], acc[i][j]);
    __syncthreads();
  }

  #pragma unroll
  for(int i=0;i<2;i++)
    #pragma unroll
    for(int j=0;j<2;j++)
      #pragma unroll
      for(int r=0;r<4;r++){
        int gm = m0 + wm*32 + i*16 + hi*4 + r;
        int gn = n0 + wn*32 + j*16 + ln15;
        C[(size_t)gm*CXX + gn] = acc[i][j][r] * mul[(size_t)gm*CXX + gn];
      }
}

// ---------------- barrier-free flash attention, swapped QK^T (S^T = K Q^T) ----------
// grid (32, 16, KSPLIT). Each lane owns ONE q-row (q = q0 + w*16 + ln15).
// S^T frag: sreg[jt][r] = S^T[key=jt*16+hi*4+r][q=ln15] -> pair/mask vectorize over r,
// softmax is lane-local + 2 shuffles. P^T packed to LDS (stride-36 u32 rows),
// read back as B-frag for O^T = V^T P^T. No __syncthreads.
__global__ __launch_bounds__(256) void attn_mfma(const unsigned short* __restrict__ qkvg,
    const unsigned short* __restrict__ vt, const float* __restrict__ pair,
    const int* __restrict__ mask, float* __restrict__ po, float* __restrict__ pm,
    float* __restrict__ pl){
  const int h = blockIdx.y;
  const int q0 = blockIdx.x*64;
  const int kz = blockIdx.z;
  const int kbase = kz*(NN/KSPLIT);
  const int NT = (NN/KSPLIT)/64;    // 8
  const int tid = threadIdx.x;
  const int w = tid>>6, lane = tid&63;
  const int ln15 = lane&15, hi = lane>>4;
  const int q = q0 + w*16 + ln15;

  __shared__ unsigned int Pw[4][16*36];
  unsigned int* Pme = &Pw[w][0];

  const float scale = 0.14433756729740643f;
  f32x4 z = {0.f,0.f,0.f,0.f};

  // B-frag Q: lane(ln15,hi) holds Q[q=ln15-row][d=hi*8..+7]
  const unsigned short* qp = qkvg + (size_t)q*3072 + h*DHH + hi*8;
  bf16x8 bq0 = *(const bf16x8*)qp;
  bf16x8 bq1 = *(const bf16x8*)(qp + 32);
  if(hi >= 2){ bf16x8 z8 = {0,0,0,0,0,0,0,0}; bq1 = z8; }   // d>=48 padding

  f32x4 oacc[3] = {z,z,z};
  float m_run = -1e30f, l_run = 0.f;

  bf16x8 kf0[2][4], kf1[2][4];   // K A-frags, double buffered (1 tile ahead)
  float4 pf[2][4];               // pair, prefetched 2 tiles ahead

  const float* pbase = pair + ((size_t)h*NN + q)*NN;

  // ---- prologue: K tile 0, pair tiles 0 and 1 ----
  #pragma unroll
  for(int jt=0;jt<4;jt++){
    const unsigned short* kp = qkvg + (size_t)(kbase + jt*16 + ln15)*3072 + 768 + h*DHH + hi*8;
    kf0[0][jt] = *(const bf16x8*)kp;
    kf1[0][jt] = *(const bf16x8*)(kp+32);
    pf[0][jt] = *(const float4*)&pbase[kbase + jt*16 + hi*4];
    pf[1][jt] = *(const float4*)&pbase[kbase + 64 + jt*16 + hi*4];
  }

  for(int t=0; t<NT; ++t){
    const int B = t&1;
    const int kk = kbase + t*64;

    // mask (L1-hot) + V (L2-hot) loads for this tile
    int4 mk[4];
    #pragma unroll
    for(int jt=0;jt<4;jt++) mk[jt] = *(const int4*)&mask[kk + jt*16 + hi*4];
    bf16x8 vf0[3], vf1[3];
    #pragma unroll
    for(int dt=0;dt<3;dt++){
      const unsigned short* vp = vt + (size_t)(h*DHH + dt*16 + ln15)*NN + kk + hi*8;
      vf0[dt] = *(const bf16x8*)vp;
      vf1[dt] = *(const bf16x8*)(vp + 32);
    }

    // S^T = K Q^T
    f32x4 sreg[4];
    __builtin_amdgcn_s_setprio(1);
    #pragma unroll
    for(int jt=0;jt<4;jt++){
      f32x4 s = z;
      s = MFMA16(kf0[B][jt], bq0, s);
      s = MFMA16(kf1[B][jt], bq1, s);
      sreg[jt] = s;
    }
    __builtin_amdgcn_s_setprio(0);

    // prefetch K for tile t+1
    {
      int kn = (t+1 < NT) ? kk + 64 : kbase;
      #pragma unroll
      for(int jt=0;jt<4;jt++){
        const unsigned short* kp = qkvg + (size_t)(kn + jt*16 + ln15)*3072 + 768 + h*DHH + hi*8;
        kf0[B^1][jt] = *(const bf16x8*)kp;
        kf1[B^1][jt] = *(const bf16x8*)(kp+32);
      }
    }

    // scale + pair + mask (consume pf[B]), then prefetch pair for tile t+2 into pf[B]
    float sv[4][4];
    #pragma unroll
    for(int jt=0;jt<4;jt++){
      sv[jt][0] = mk[jt].x ? sreg[jt][0]*scale + pf[B][jt].x : -1e9f;
      sv[jt][1] = mk[jt].y ? sreg[jt][1]*scale + pf[B][jt].y : -1e9f;
      sv[jt][2] = mk[jt].z ? sreg[jt][2]*scale + pf[B][jt].z : -1e9f;
      sv[jt][3] = mk[jt].w ? sreg[jt][3]*scale + pf[B][jt].w : -1e9f;
    }
    {
      int kn2 = (t+2 < NT) ? kk + 128 : kbase;
      #pragma unroll
      for(int jt=0;jt<4;jt++)
        pf[B][jt] = *(const float4*)&pbase[kn2 + jt*16 + hi*4];
    }

    // online softmax: per-lane q-row, 16 local values + cross-hi reduce
    float vmax = sv[0][0];
    #pragma unroll
    for(int jt=0;jt<4;jt++)
      #pragma unroll
      for(int r=0;r<4;r++) vmax = fmaxf(vmax, sv[jt][r]);
    vmax = fmaxf(vmax, __shfl_xor(vmax,16));
    vmax = fmaxf(vmax, __shfl_xor(vmax,32));
    float mn = fmaxf(m_run, vmax);
    float al = __expf(m_run - mn);
    m_run = mn;
    float pv[4][4];
    float rs = 0.f;
    #pragma unroll
    for(int jt=0;jt<4;jt++)
      #pragma unroll
      for(int r=0;r<4;r++){
        pv[jt][r] = __expf(sv[jt][r] - mn);
        rs += pv[jt][r];
      }
    rs += __shfl_xor(rs,16);
    rs += __shfl_xor(rs,32);
    l_run = l_run*al + rs;

    // pack P^T -> LDS: row q=ln15 (stride 36 u32), word index = key/2 = jt*8+hi*2+w
    #pragma unroll
    for(int jt=0;jt<4;jt++){
      unsigned int w0 = (unsigned)f2bf(pv[jt][0]) | ((unsigned)f2bf(pv[jt][1])<<16);
      unsigned int w1 = (unsigned)f2bf(pv[jt][2]) | ((unsigned)f2bf(pv[jt][3])<<16);
      *(uint2*)&Pme[ln15*36 + jt*8 + hi*2] = make_uint2(w0,w1);
    }
    __asm__ volatile("s_waitcnt lgkmcnt(0)" ::: "memory");
    __builtin_amdgcn_sched_barrier(0);

    #pragma unroll
    for(int dt=0;dt<3;dt++)
      #pragma unroll
      for(int r=0;r<4;r++) oacc[dt][r] *= al;

    // B-frag P^T: lane(ln15,hi) needs keys hi*8..+7 for q=ln15 -> words hi*4..+3
    bf16x8 bp0 = *(const bf16x8*)&Pme[ln15*36 + hi*4];
    bf16x8 bp1 = *(const bf16x8*)&Pme[ln15*36 + 16 + hi*4];
    __builtin_amdgcn_s_setprio(1);
    #pragma unroll
    for(int dt=0;dt<3;dt++){
      oacc[dt] = MFMA16(vf0[dt], bp0, oacc[dt]);
      oacc[dt] = MFMA16(vf1[dt], bp1, oacc[dt]);
    }
    __builtin_amdgcn_s_setprio(0);
  }

  // epilogue: unnormalized partial O (O[q][d] = oacc[dt][r], d=dt*16+hi*4+r) + (m,l)
  size_t rowi = ((size_t)(kz*HH + h))*NN + q;
  #pragma unroll
  for(int dt=0;dt<3;dt++){
    float4 o4;
    o4.x = oacc[dt][0]; o4.y = oacc[dt][1]; o4.z = oacc[dt][2]; o4.w = oacc[dt][3];
    *(float4*)&po[rowi*DHH + dt*16 + hi*4] = o4;
  }
  if(hi==0){ pm[rowi] = m_run; pl[rowi] = l_run; }
}

// ---------------- split-K combine + gate ----------------
__global__ __launch_bounds__(256) void attn_combine(const float* __restrict__ po,
    const float* __restrict__ pm, const float* __restrict__ pl,
    const unsigned short* __restrict__ qkvg, unsigned short* __restrict__ wag){
  const int row = blockIdx.x*4 + (threadIdx.x>>6);
  const int lane = threadIdx.x & 63;
  #pragma unroll
  for(int i=0;i<12;i++){
    int c = lane + i*64;          // 0..767
    int hh = c / DHH, d = c - hh*DHH;
    float mv[KSPLIT];
    float M = -1e30f;
    #pragma unroll
    for(int s=0;s<KSPLIT;s++){
      mv[s] = pm[((size_t)(s*HH + hh))*NN + row];
      M = fmaxf(M, mv[s]);
    }
    float L = 0.f, V = 0.f;
    #pragma unroll
    for(int s=0;s<KSPLIT;s++){
      size_t rr = ((size_t)(s*HH + hh))*NN + row;
      float e = __expf(mv[s] - M);
      L += pl[rr]*e;
      V += po[rr*DHH + d]*e;
    }
    float g = bf2f(qkvg[(size_t)row*3072 + 2304 + c]);
    wag[(size_t)row*CXX + c] = f2bf((V/L) * g);
  }
}

extern "C" void kernel_launch(void* const* d_in, const int* in_sizes, int n_in,
                              void* d_out, int out_size, void* d_ws, size_t ws_size,
                              hipStream_t stream) {
  const float* x           = (const float*)d_in[0];
  const int*   mask        = (const int*)  d_in[1];
  const float* pair        = (const float*)d_in[2];
  const float* single_cond = (const float*)d_in[3];
  const float* ln_sc_w     = (const float*)d_in[4];
  const float* sc_scale_w  = (const float*)d_in[5];
  const float* sc_scale_b  = (const float*)d_in[6];
  const float* sc_bias_w   = (const float*)d_in[7];
  const float* q_w         = (const float*)d_in[8];
  const float* q_b         = (const float*)d_in[9];
  const float* k_w         = (const float*)d_in[10];
  const float* v_w         = (const float*)d_in[11];
  const float* gate_w      = (const float*)d_in[12];
  const float* out_w       = (const float*)d_in[13];
  const float* azc_w       = (const float*)d_in[14];
  const float* azc_b       = (const float*)d_in[15];
  float* out = (float*)d_out;

  unsigned short* p = (unsigned short*)d_ws;
  unsigned short* Wt_scale = p;  p += 768*384;
  unsigned short* Wt_bias  = p;  p += 768*384;
  unsigned short* Wt_azc   = p;  p += 768*384;
  unsigned short* Wt_out   = p;  p += 768*768;
  unsigned short* Wt_qkvg  = p;  p += (size_t)3072*768;
  unsigned short* scb      = p;  p += 2048*384;
  unsigned short* xa       = p;  p += 2048*768;
  unsigned short* qkvg     = p;  p += (size_t)2048*3072;
  unsigned short* wag      = p;  p += 2048*768;
  unsigned short* vt       = p;  p += (size_t)768*2048;
  float* fp = (float*)p;
  float* xn  = fp; fp += (size_t)2048*768;
  float* azc = fp; fp += (size_t)2048*768;
  float* po  = fp; fp += (size_t)KSPLIT*HH*NN*DHH;
  float* pm  = fp; fp += (size_t)KSPLIT*HH*NN;
  float* pl  = fp;

  transpose_all<<<dim3(24,24,8), 256, 0, stream>>>(
      sc_scale_w, sc_bias_w, azc_w, q_w, k_w, v_w, gate_w, out_w,
      Wt_scale, Wt_bias, Wt_azc, Wt_qkvg, Wt_out);

  ln_fused<<<NN, 384, 0, stream>>>(x, single_cond, ln_sc_w, xn, scb);

  adaln3<<<dim3(12,32), 256, 0, stream>>>(scb, Wt_scale, Wt_bias, Wt_azc,
                                          sc_scale_b, azc_b, xn, xa, azc);

  gemm_qkvg<<<dim3(24,16), 256, 0, stream>>>(xa, Wt_qkvg, q_b, qkvg, vt);

  attn_mfma<<<dim3(32,16,KSPLIT), 256, 0, stream>>>(qkvg, vt, pair, mask, po, pm, pl);

  attn_combine<<<512, 256, 0, stream>>>(po, pm, pl, qkvg, wag);

  gemm_out<<<dim3(12,32), 256, 0, stream>>>(wag, Wt_out, azc, out);
}

// Round 5
// 566.335 us; speedup vs baseline: 5.9398x; 5.9398x over previous
//
#include <hip/hip_runtime.h>
#include <math.h>

#define NN 2048
#define CXX 768
#define CSS 384
#define HH 16
#define DHH 48
#define KSPLIT 4

typedef short bf16x8 __attribute__((ext_vector_type(8)));
typedef float f32x4 __attribute__((ext_vector_type(4)));

#define MFMA16(a,b,c) __builtin_amdgcn_mfma_f32_16x16x32_bf16(a,b,c,0,0,0)

__device__ __forceinline__ unsigned short f2bf(float f){
  unsigned u = __float_as_uint(f);
  u += 0x7FFFu + ((u >> 16) & 1u);
  return (unsigned short)(u >> 16);
}
__device__ __forceinline__ float bf2f(unsigned short u){
  return __uint_as_float(((unsigned)u) << 16);
}
__device__ __forceinline__ void async_copy16(const void* g, void* l){
  __builtin_amdgcn_global_load_lds((const __attribute__((address_space(1))) void*)g,
                                   (__attribute__((address_space(3))) void*)l, 16, 0, 0);
}

__device__ inline float waveReduceSum(float v){
  #pragma unroll
  for(int o=32;o>0;o>>=1) v += __shfl_xor(v,o);
  return v;
}

// ---------------- batched weight fp32 -> bf16 transpose (all 8 matrices) ----------
__global__ __launch_bounds__(256) void transpose_all(
    const float* __restrict__ s0, const float* __restrict__ s1, const float* __restrict__ s2,
    const float* __restrict__ s3, const float* __restrict__ s4, const float* __restrict__ s5,
    const float* __restrict__ s6, const float* __restrict__ s7,
    unsigned short* __restrict__ d_scale, unsigned short* __restrict__ d_bias,
    unsigned short* __restrict__ d_azc, unsigned short* __restrict__ d_qkvg,
    unsigned short* __restrict__ d_out){
  int z = blockIdx.z;
  const float* W; unsigned short* Wt; int K;
  switch(z){
    case 0: W=s0; Wt=d_scale; K=384; break;
    case 1: W=s1; Wt=d_bias;  K=384; break;
    case 2: W=s2; Wt=d_azc;   K=384; break;
    case 3: W=s3; Wt=d_qkvg + 0*589824; K=768; break;
    case 4: W=s4; Wt=d_qkvg + 1*589824; K=768; break;
    case 5: W=s5; Wt=d_qkvg + 2*589824; K=768; break;
    case 6: W=s6; Wt=d_qkvg + 3*589824; K=768; break;
    default: W=s7; Wt=d_out; K=768; break;
  }
  int n0 = blockIdx.x*32, k0 = blockIdx.y*32;
  if(k0 >= K) return;
  __shared__ unsigned short t[32][33];
  int c = threadIdx.x & 31, r = threadIdx.x >> 5;
  #pragma unroll
  for(int i=0;i<32;i+=8){
    float v = W[(size_t)(k0 + r + i)*CXX + n0 + c];
    t[c][r+i] = f2bf(v);
  }
  __syncthreads();
  #pragma unroll
  for(int i=0;i<32;i+=8){
    Wt[(size_t)(n0 + r + i)*K + k0 + c] = t[r+i][c];
  }
}

// ---------------- fused LayerNorms: x (fp32 out) + single_cond (bf16 out) ----------
__global__ __launch_bounds__(384) void ln_fused(const float* __restrict__ x,
    const float* __restrict__ scin, const float* __restrict__ w,
    float* __restrict__ xn, unsigned short* __restrict__ scb){
  int row = blockIdx.x;
  int t = threadIdx.x;
  int wid = t>>6, lane = t&63;
  __shared__ float red[6];
  float a0 = x[(size_t)row*CXX + t];
  float a1 = x[(size_t)row*CXX + 384 + t];
  float s = waveReduceSum(a0+a1);
  if(lane==0) red[wid]=s;
  __syncthreads();
  float mu = (red[0]+red[1]+red[2]+red[3]+red[4]+red[5]) * (1.0f/CXX);
  float d0=a0-mu, d1=a1-mu;
  float q = waveReduceSum(d0*d0+d1*d1);
  __syncthreads();
  if(lane==0) red[wid]=q;
  __syncthreads();
  float var = (red[0]+red[1]+red[2]+red[3]+red[4]+red[5]) * (1.0f/CXX);
  float r = rsqrtf(var + 1e-5f);
  xn[(size_t)row*CXX + t] = d0*r;
  xn[(size_t)row*CXX + 384 + t] = d1*r;
  float b = scin[(size_t)row*CSS + t];
  float s2 = waveReduceSum(b);
  __syncthreads();
  if(lane==0) red[wid]=s2;
  __syncthreads();
  float mu2 = (red[0]+red[1]+red[2]+red[3]+red[4]+red[5]) * (1.0f/CSS);
  float d2 = b - mu2;
  float q2 = waveReduceSum(d2*d2);
  __syncthreads();
  if(lane==0) red[wid]=q2;
  __syncthreads();
  float var2 = (red[0]+red[1]+red[2]+red[3]+red[4]+red[5]) * (1.0f/CSS);
  float r2 = rsqrtf(var2 + 1e-5f);
  scb[(size_t)row*CSS + t] = f2bf(d2*r2*w[t]);
}

// ---------------- qkvg GEMM (128x128 tile, BK=32): q/k/gate -> qkvg, v -> vt^T ------
__global__ __launch_bounds__(256) void gemm_qkvg(const unsigned short* __restrict__ A,
    const unsigned short* __restrict__ Bt, const float* __restrict__ bias,
    unsigned short* __restrict__ C, unsigned short* __restrict__ vt){
  __shared__ unsigned short As[128*32];
  __shared__ unsigned short Bs[128*32];
  const int tid = threadIdx.x;
  const int w = tid>>6, lane = tid&63;
  const int ln15 = lane&15, hi = lane>>4;
  const int wm = w&1, wn = w>>1;
  const int m0 = blockIdx.y*128, n0 = blockIdx.x*128;
  const int lrow = lane>>2, lk = (lane&3)*8;
  const int K = 768, NC = 3072;

  f32x4 z = {0.f,0.f,0.f,0.f};
  f32x4 acc[4][4];
  #pragma unroll
  for(int i=0;i<4;i++)
    #pragma unroll
    for(int j=0;j<4;j++) acc[i][j] = z;

  for(int k0=0;k0<K;k0+=32){
    const unsigned short* ga = A + (size_t)(m0 + w*32 + lrow)*K + k0 + lk;
    const unsigned short* gb = Bt + (size_t)(n0 + w*32 + lrow)*K + k0 + lk;
    async_copy16(ga,          &As[w*1024]);
    async_copy16(ga + 16*K,   &As[w*1024 + 512]);
    async_copy16(gb,          &Bs[w*1024]);
    async_copy16(gb + 16*K,   &Bs[w*1024 + 512]);
    __syncthreads();
    bf16x8 af[4], bfr[4];
    #pragma unroll
    for(int i=0;i<4;i++) af[i]  = *(const bf16x8*)&As[(wm*64 + i*16 + ln15)*32 + hi*8];
    #pragma unroll
    for(int j=0;j<4;j++) bfr[j] = *(const bf16x8*)&Bs[(wn*64 + j*16 + ln15)*32 + hi*8];
    #pragma unroll
    for(int i=0;i<4;i++)
      #pragma unroll
      for(int j=0;j<4;j++)
        acc[i][j] = MFMA16(af[i], bfr[j], acc[i][j]);
    __syncthreads();
  }

  #pragma unroll
  for(int i=0;i<4;i++)
    #pragma unroll
    for(int j=0;j<4;j++){
      int gm0 = m0 + wm*64 + i*16 + hi*4;
      int gn  = n0 + wn*64 + j*16 + ln15;
      if(gn >= 1536 && gn < 2304){
        // V projection: store transposed vt[d_global][key], keys contiguous
        ushort4 v4;
        v4.x = f2bf(acc[i][j][0]);
        v4.y = f2bf(acc[i][j][1]);
        v4.z = f2bf(acc[i][j][2]);
        v4.w = f2bf(acc[i][j][3]);
        *(ushort4*)&vt[(size_t)(gn - 1536)*NN + gm0] = v4;
      } else {
        #pragma unroll
        for(int r=0;r<4;r++){
          float v = acc[i][j][r];
          if(gn < 768) v += bias[gn];
          if(gn >= 2304) v = 1.0f/(1.0f + __expf(-v));
          C[(size_t)(gm0+r)*NC + gn] = f2bf(v);
        }
      }
    }
}

// ---------------- AdaLN triple-GEMM (64x64 tile, BK=32, 384 blocks) ----------------
__global__ __launch_bounds__(256) void adaln3(const unsigned short* __restrict__ A,
    const unsigned short* __restrict__ B1, const unsigned short* __restrict__ B2,
    const unsigned short* __restrict__ B3, const float* __restrict__ bs,
    const float* __restrict__ zb, const float* __restrict__ xn,
    unsigned short* __restrict__ xa, float* __restrict__ azc){
  __shared__ unsigned short As[64*32];
  __shared__ unsigned short Bs1[64*32];
  __shared__ unsigned short Bs2[64*32];
  __shared__ unsigned short Bs3[64*32];
  const int tid = threadIdx.x;
  const int w = tid>>6, lane = tid&63;
  const int ln15 = lane&15, hi = lane>>4;
  const int wm = w&1, wn = w>>1;
  const int m0 = blockIdx.y*64, n0 = blockIdx.x*64;
  const int lrow = tid>>2, lk = (tid&3)*8;
  const int K = CSS;

  f32x4 z = {0.f,0.f,0.f,0.f};
  f32x4 acc1[2][2], acc2[2][2], acc3[2][2];
  #pragma unroll
  for(int i=0;i<2;i++)
    #pragma unroll
    for(int j=0;j<2;j++){ acc1[i][j]=z; acc2[i][j]=z; acc3[i][j]=z; }

  for(int k0=0;k0<K;k0+=32){
    async_copy16(A  + (size_t)(m0+lrow)*K + k0 + lk, &As [w*512]);
    async_copy16(B1 + (size_t)(n0+lrow)*K + k0 + lk, &Bs1[w*512]);
    async_copy16(B2 + (size_t)(n0+lrow)*K + k0 + lk, &Bs2[w*512]);
    async_copy16(B3 + (size_t)(n0+lrow)*K + k0 + lk, &Bs3[w*512]);
    __syncthreads();
    bf16x8 af[2], b1f[2], b2f[2], b3f[2];
    #pragma unroll
    for(int i=0;i<2;i++) af[i]  = *(const bf16x8*)&As[(wm*32 + i*16 + ln15)*32 + hi*8];
    #pragma unroll
    for(int j=0;j<2;j++){
      b1f[j] = *(const bf16x8*)&Bs1[(wn*32 + j*16 + ln15)*32 + hi*8];
      b2f[j] = *(const bf16x8*)&Bs2[(wn*32 + j*16 + ln15)*32 + hi*8];
      b3f[j] = *(const bf16x8*)&Bs3[(wn*32 + j*16 + ln15)*32 + hi*8];
    }
    #pragma unroll
    for(int i=0;i<2;i++)
      #pragma unroll
      for(int j=0;j<2;j++){
        acc1[i][j] = MFMA16(af[i], b1f[j], acc1[i][j]);
        acc2[i][j] = MFMA16(af[i], b2f[j], acc2[i][j]);
        acc3[i][j] = MFMA16(af[i], b3f[j], acc3[i][j]);
      }
    __syncthreads();
  }

  #pragma unroll
  for(int i=0;i<2;i++)
    #pragma unroll
    for(int j=0;j<2;j++)
      #pragma unroll
      for(int r=0;r<4;r++){
        int gm = m0 + wm*32 + i*16 + hi*4 + r;
        int gn = n0 + wn*32 + j*16 + ln15;
        float g = 1.0f/(1.0f + __expf(-(acc1[i][j][r] + bs[gn])));
        float v = g * xn[(size_t)gm*CXX + gn] + acc2[i][j][r];
        xa[(size_t)gm*CXX + gn] = f2bf(v);
        azc[(size_t)gm*CXX + gn] = 1.0f/(1.0f + __expf(-(acc3[i][j][r] + zb[gn])));
      }
}

// ---------------- out GEMM (64x64 tile, BK=32): out = (wag @ out_w) * azc, fp32 ----------
__global__ __launch_bounds__(256) void gemm_out(const unsigned short* __restrict__ A,
    const unsigned short* __restrict__ Bt, const float* __restrict__ mul,
    float* __restrict__ C){
  __shared__ unsigned short As[64*32];
  __shared__ unsigned short Bs[64*32];
  const int tid = threadIdx.x;
  const int w = tid>>6, lane = tid&63;
  const int ln15 = lane&15, hi = lane>>4;
  const int wm = w&1, wn = w>>1;
  const int m0 = blockIdx.y*64, n0 = blockIdx.x*64;
  const int lrow = tid>>2, lk = (tid&3)*8;
  const int K = 768;

  f32x4 z = {0.f,0.f,0.f,0.f};
  f32x4 acc[2][2];
  #pragma unroll
  for(int i=0;i<2;i++)
    #pragma unroll
    for(int j=0;j<2;j++) acc[i][j]=z;

  for(int k0=0;k0<K;k0+=32){
    async_copy16(A  + (size_t)(m0+lrow)*K + k0 + lk, &As[w*512]);
    async_copy16(Bt + (size_t)(n0+lrow)*K + k0 + lk, &Bs[w*512]);
    __syncthreads();
    bf16x8 af[2], bfr[2];
    #pragma unroll
    for(int i=0;i<2;i++) af[i]  = *(const bf16x8*)&As[(wm*32 + i*16 + ln15)*32 + hi*8];
    #pragma unroll
    for(int j=0;j<2;j++) bfr[j] = *(const bf16x8*)&Bs[(wn*32 + j*16 + ln15)*32 + hi*8];
    #pragma unroll
    for(int i=0;i<2;i++)
      #pragma unroll
      for(int j=0;j<2;j++)
        acc[i][j] = MFMA16(af[i], bfr[j], acc[i][j]);
    __syncthreads();
  }

  #pragma unroll
  for(int i=0;i<2;i++)
    #pragma unroll
    for(int j=0;j<2;j++)
      #pragma unroll
      for(int r=0;r<4;r++){
        int gm = m0 + wm*32 + i*16 + hi*4 + r;
        int gn = n0 + wn*32 + j*16 + ln15;
        C[(size_t)gm*CXX + gn] = acc[i][j][r] * mul[(size_t)gm*CXX + gn];
      }
}

// ---------------- barrier-free flash attention, swapped QK^T (S^T = K Q^T) ----------
// grid (32, 16, KSPLIT). Each lane owns ONE q-row (q = q0 + w*16 + ln15).
// Double buffers are NAMED register arrays (compile-time indices only — rule #20).
// K prefetched 1 tile ahead, pair 2 tiles ahead. No __syncthreads.

#define ATTN_STEP(KF0C, KF1C, PFC, KF0N, KF1N, KK, KNXT, KP2) do{                  \
    int4 mk[4];                                                                    \
    _Pragma("unroll")                                                              \
    for(int jt=0;jt<4;jt++) mk[jt] = *(const int4*)&mask[(KK) + jt*16 + hi*4];     \
    bf16x8 vf0[3], vf1[3];                                                         \
    _Pragma("unroll")                                                              \
    for(int dt=0;dt<3;dt++){                                                       \
      const unsigned short* vp_ = vt + (size_t)(h*DHH + dt*16 + ln15)*NN + (KK) + hi*8; \
      vf0[dt] = *(const bf16x8*)vp_;                                               \
      vf1[dt] = *(const bf16x8*)(vp_ + 32);                                        \
    }                                                                              \
    f32x4 sreg[4];                                                                 \
    __builtin_amdgcn_s_setprio(1);                                                 \
    _Pragma("unroll")                                                              \
    for(int jt=0;jt<4;jt++){                                                       \
      f32x4 s_ = z;                                                                \
      s_ = MFMA16(KF0C[jt], bq0, s_);                                              \
      s_ = MFMA16(KF1C[jt], bq1, s_);                                              \
      sreg[jt] = s_;                                                               \
    }                                                                              \
    __builtin_amdgcn_s_setprio(0);                                                 \
    _Pragma("unroll")                                                              \
    for(int jt=0;jt<4;jt++){                                                       \
      const unsigned short* kp_ = qkvg + (size_t)((KNXT) + jt*16 + ln15)*3072 + 768 + h*DHH + hi*8; \
      KF0N[jt] = *(const bf16x8*)kp_;                                              \
      KF1N[jt] = *(const bf16x8*)(kp_ + 32);                                       \
    }                                                                              \
    float sv[4][4];                                                                \
    _Pragma("unroll")                                                              \
    for(int jt=0;jt<4;jt++){                                                       \
      sv[jt][0] = mk[jt].x ? sreg[jt][0]*scale + PFC[jt].x : -1e9f;                \
      sv[jt][1] = mk[jt].y ? sreg[jt][1]*scale + PFC[jt].y : -1e9f;                \
      sv[jt][2] = mk[jt].z ? sreg[jt][2]*scale + PFC[jt].z : -1e9f;                \
      sv[jt][3] = mk[jt].w ? sreg[jt][3]*scale + PFC[jt].w : -1e9f;                \
    }                                                                              \
    _Pragma("unroll")                                                              \
    for(int jt=0;jt<4;jt++)                                                        \
      PFC[jt] = *(const float4*)&pbase[(KP2) + jt*16 + hi*4];                      \
    float vmax = sv[0][0];                                                         \
    _Pragma("unroll")                                                              \
    for(int jt=0;jt<4;jt++)                                                        \
      _Pragma("unroll")                                                            \
      for(int r=0;r<4;r++) vmax = fmaxf(vmax, sv[jt][r]);                          \
    vmax = fmaxf(vmax, __shfl_xor(vmax,16));                                       \
    vmax = fmaxf(vmax, __shfl_xor(vmax,32));                                       \
    float mn = fmaxf(m_run, vmax);                                                 \
    float al = __expf(m_run - mn);                                                 \
    m_run = mn;                                                                    \
    float pv[4][4];                                                                \
    float rs = 0.f;                                                                \
    _Pragma("unroll")                                                              \
    for(int jt=0;jt<4;jt++)                                                        \
      _Pragma("unroll")                                                            \
      for(int r=0;r<4;r++){                                                        \
        pv[jt][r] = __expf(sv[jt][r] - mn);                                        \
        rs += pv[jt][r];                                                           \
      }                                                                            \
    rs += __shfl_xor(rs,16);                                                       \
    rs += __shfl_xor(rs,32);                                                       \
    l_run = l_run*al + rs;                                                         \
    _Pragma("unroll")                                                              \
    for(int jt=0;jt<4;jt++){                                                       \
      unsigned int w0_ = (unsigned)f2bf(pv[jt][0]) | ((unsigned)f2bf(pv[jt][1])<<16); \
      unsigned int w1_ = (unsigned)f2bf(pv[jt][2]) | ((unsigned)f2bf(pv[jt][3])<<16); \
      *(uint2*)&Pme[ln15*36 + jt*8 + hi*2] = make_uint2(w0_,w1_);                  \
    }                                                                              \
    __asm__ volatile("s_waitcnt lgkmcnt(0)" ::: "memory");                         \
    __builtin_amdgcn_sched_barrier(0);                                             \
    _Pragma("unroll")                                                              \
    for(int dt=0;dt<3;dt++)                                                        \
      _Pragma("unroll")                                                            \
      for(int r=0;r<4;r++) oacc[dt][r] *= al;                                      \
    bf16x8 bp0 = *(const bf16x8*)&Pme[ln15*36 + hi*4];                             \
    bf16x8 bp1 = *(const bf16x8*)&Pme[ln15*36 + 16 + hi*4];                        \
    __builtin_amdgcn_s_setprio(1);                                                 \
    _Pragma("unroll")                                                              \
    for(int dt=0;dt<3;dt++){                                                       \
      oacc[dt] = MFMA16(vf0[dt], bp0, oacc[dt]);                                   \
      oacc[dt] = MFMA16(vf1[dt], bp1, oacc[dt]);                                   \
    }                                                                              \
    __builtin_amdgcn_s_setprio(0);                                                 \
  }while(0)

__global__ __launch_bounds__(256) void attn_mfma(const unsigned short* __restrict__ qkvg,
    const unsigned short* __restrict__ vt, const float* __restrict__ pair,
    const int* __restrict__ mask, float* __restrict__ po, float* __restrict__ pm,
    float* __restrict__ pl){
  const int h = blockIdx.y;
  const int q0 = blockIdx.x*64;
  const int kz = blockIdx.z;
  const int kbase = kz*(NN/KSPLIT);
  const int NT = (NN/KSPLIT)/64;    // 8
  const int tid = threadIdx.x;
  const int w = tid>>6, lane = tid&63;
  const int ln15 = lane&15, hi = lane>>4;
  const int q = q0 + w*16 + ln15;

  __shared__ unsigned int Pw[4][16*36];
  unsigned int* Pme = &Pw[w][0];

  const float scale = 0.14433756729740643f;
  f32x4 z = {0.f,0.f,0.f,0.f};

  // B-frag Q: lane(ln15,hi) holds Q[q=ln15-row][d=hi*8..+7]
  const unsigned short* qp = qkvg + (size_t)q*3072 + h*DHH + hi*8;
  bf16x8 bq0 = *(const bf16x8*)qp;
  bf16x8 bq1 = *(const bf16x8*)(qp + 32);
  if(hi >= 2){ bf16x8 z8 = {0,0,0,0,0,0,0,0}; bq1 = z8; }   // d>=48 padding

  f32x4 oacc[3] = {z,z,z};
  float m_run = -1e30f, l_run = 0.f;

  // named double buffers — all indices compile-time (rule #20)
  bf16x8 kf0a[4], kf1a[4], kf0b[4], kf1b[4];
  float4 pfa[4], pfb[4];

  const float* pbase = pair + ((size_t)h*NN + q)*NN;

  // ---- prologue: K tile 0 -> a, pair tile 0 -> a, pair tile 1 -> b ----
  #pragma unroll
  for(int jt=0;jt<4;jt++){
    const unsigned short* kp = qkvg + (size_t)(kbase + jt*16 + ln15)*3072 + 768 + h*DHH + hi*8;
    kf0a[jt] = *(const bf16x8*)kp;
    kf1a[jt] = *(const bf16x8*)(kp+32);
    pfa[jt] = *(const float4*)&pbase[kbase + jt*16 + hi*4];
    pfb[jt] = *(const float4*)&pbase[kbase + 64 + jt*16 + hi*4];
  }

  for(int t=0; t<NT; t+=2){
    const int kk = kbase + t*64;
    const int kp2a = (t+2 < NT) ? kk + 128 : kbase;  // pair prefetch for tile t+2
    const int kp2b = (t+3 < NT) ? kk + 192 : kbase;  // pair prefetch for tile t+3
    const int knb  = (t+2 < NT) ? kk + 128 : kbase;  // K prefetch for tile t+2
    // tile t   : consume a, prefetch K(t+1)->b, pair(t+2)->a
    ATTN_STEP(kf0a, kf1a, pfa, kf0b, kf1b, kk,      kk+64, kp2a);
    // tile t+1 : consume b, prefetch K(t+2)->a, pair(t+3)->b
    ATTN_STEP(kf0b, kf1b, pfb, kf0a, kf1a, kk+64,   knb,   kp2b);
  }

  // epilogue: unnormalized partial O (O[q][d] = oacc[dt][r], d=dt*16+hi*4+r) + (m,l)
  size_t rowi = ((size_t)(kz*HH + h))*NN + q;
  #pragma unroll
  for(int dt=0;dt<3;dt++){
    float4 o4;
    o4.x = oacc[dt][0]; o4.y = oacc[dt][1]; o4.z = oacc[dt][2]; o4.w = oacc[dt][3];
    *(float4*)&po[rowi*DHH + dt*16 + hi*4] = o4;
  }
  if(hi==0){ pm[rowi] = m_run; pl[rowi] = l_run; }
}

// ---------------- split-K combine + gate ----------------
__global__ __launch_bounds__(256) void attn_combine(const float* __restrict__ po,
    const float* __restrict__ pm, const float* __restrict__ pl,
    const unsigned short* __restrict__ qkvg, unsigned short* __restrict__ wag){
  const int row = blockIdx.x*4 + (threadIdx.x>>6);
  const int lane = threadIdx.x & 63;
  #pragma unroll
  for(int i=0;i<12;i++){
    int c = lane + i*64;          // 0..767
    int hh = c / DHH, d = c - hh*DHH;
    float mv[KSPLIT];
    float M = -1e30f;
    #pragma unroll
    for(int s=0;s<KSPLIT;s++){
      mv[s] = pm[((size_t)(s*HH + hh))*NN + row];
      M = fmaxf(M, mv[s]);
    }
    float L = 0.f, V = 0.f;
    #pragma unroll
    for(int s=0;s<KSPLIT;s++){
      size_t rr = ((size_t)(s*HH + hh))*NN + row;
      float e = __expf(mv[s] - M);
      L += pl[rr]*e;
      V += po[rr*DHH + d]*e;
    }
    float g = bf2f(qkvg[(size_t)row*3072 + 2304 + c]);
    wag[(size_t)row*CXX + c] = f2bf((V/L) * g);
  }
}

extern "C" void kernel_launch(void* const* d_in, const int* in_sizes, int n_in,
                              void* d_out, int out_size, void* d_ws, size_t ws_size,
                              hipStream_t stream) {
  const float* x           = (const float*)d_in[0];
  const int*   mask        = (const int*)  d_in[1];
  const float* pair        = (const float*)d_in[2];
  const float* single_cond = (const float*)d_in[3];
  const float* ln_sc_w     = (const float*)d_in[4];
  const float* sc_scale_w  = (const float*)d_in[5];
  const float* sc_scale_b  = (const float*)d_in[6];
  const float* sc_bias_w   = (const float*)d_in[7];
  const float* q_w         = (const float*)d_in[8];
  const float* q_b         = (const float*)d_in[9];
  const float* k_w         = (const float*)d_in[10];
  const float* v_w         = (const float*)d_in[11];
  const float* gate_w      = (const float*)d_in[12];
  const float* out_w       = (const float*)d_in[13];
  const float* azc_w       = (const float*)d_in[14];
  const float* azc_b       = (const float*)d_in[15];
  float* out = (float*)d_out;

  unsigned short* p = (unsigned short*)d_ws;
  unsigned short* Wt_scale = p;  p += 768*384;
  unsigned short* Wt_bias  = p;  p += 768*384;
  unsigned short* Wt_azc   = p;  p += 768*384;
  unsigned short* Wt_out   = p;  p += 768*768;
  unsigned short* Wt_qkvg  = p;  p += (size_t)3072*768;
  unsigned short* scb      = p;  p += 2048*384;
  unsigned short* xa       = p;  p += 2048*768;
  unsigned short* qkvg     = p;  p += (size_t)2048*3072;
  unsigned short* wag      = p;  p += 2048*768;
  unsigned short* vt       = p;  p += (size_t)768*2048;
  float* fp = (float*)p;
  float* xn  = fp; fp += (size_t)2048*768;
  float* azc = fp; fp += (size_t)2048*768;
  float* po  = fp; fp += (size_t)KSPLIT*HH*NN*DHH;
  float* pm  = fp; fp += (size_t)KSPLIT*HH*NN;
  float* pl  = fp;

  transpose_all<<<dim3(24,24,8), 256, 0, stream>>>(
      sc_scale_w, sc_bias_w, azc_w, q_w, k_w, v_w, gate_w, out_w,
      Wt_scale, Wt_bias, Wt_azc, Wt_qkvg, Wt_out);

  ln_fused<<<NN, 384, 0, stream>>>(x, single_cond, ln_sc_w, xn, scb);

  adaln3<<<dim3(12,32), 256, 0, stream>>>(scb, Wt_scale, Wt_bias, Wt_azc,
                                          sc_scale_b, azc_b, xn, xa, azc);

  gemm_qkvg<<<dim3(24,16), 256, 0, stream>>>(xa, Wt_qkvg, q_b, qkvg, vt);

  attn_mfma<<<dim3(32,16,KSPLIT), 256, 0, stream>>>(qkvg, vt, pair, mask, po, pm, pl);

  attn_combine<<<512, 256, 0, stream>>>(po, pm, pl, qkvg, wag);

  gemm_out<<<dim3(12,32), 256, 0, stream>>>(wag, Wt_out, azc, out);
}